// Round 1
// baseline (14494.566 us; speedup 1.0000x reference)
//
#include <hip/hip_runtime.h>
#include <hip/hip_bf16.h>
#include <hip/hip_fp16.h>

// Hypernetwork RNN scan. B=16, N=2048, M=H=64, L*E=1024, Cout=256.
// Round 14: single-WG-per-batch. R13's step was ~3520 cycles of which ~3000
// was the cross-WG exchange RTT (agent-scope store -> LLC -> polling load)
// sitting on the serial chain every step. Fix: eliminate the exchange.
// At 1 WG/CU x 512 threads (2 waves/SIMD) each wave can hold ~450 regs, so
// the FULL Wd (64h x 64i x 64j f16 = 512 KB = 256 VGPRs/thread) lives in
// registers of ONE workgroup per batch. 16 WGs, zero inter-WG traffic.
//   thread (hg=tid>>6, i=tid&63) owns h-rows {s*16+2*hh+p : hh<8},
//   s=hg>>1, p=hg&1  -> reduction order bit-identical to R13's r0/r1 split.
// Per-step: V = 256 dot2f/thread (1024 cyc/CU VALU floor) -> in-register
// hw-weighted partials -> 2KB LDS 8-way sum -> m assemble. 3 barriers.
//   K1 cvt: Wd->f16 per-thread-register layout; enc m-rows->f16; dec_w->bf16
//   K2 build_T (f32, 8 MB), K3 build_P (f32, 16 MB)
//   K4 recur: 16 WGs = 16 batches; Wd entirely in VGPRs/AGPRs
//   K5 loss:  parallel logits/LSE/NLL over the f16 m history

typedef unsigned int uint_t;
typedef unsigned short us_t;
typedef _Float16 h2_t __attribute__((ext_vector_type(2)));

__device__ __forceinline__ us_t f2bf(float f) {
    uint_t u = __float_as_uint(f);
    uint_t r = u + 0x7fffu + ((u >> 16) & 1u);   // RNE
    return (us_t)(r >> 16);
}
__device__ __forceinline__ float bflo(uint_t u) { return __uint_as_float(u << 16); }
__device__ __forceinline__ float bfhi(uint_t u) { return __uint_as_float(u & 0xffff0000u); }

__device__ __forceinline__ us_t f2h(float f) {
    __half h = __float2half(f);                  // RNE
    return *reinterpret_cast<us_t*>(&h);
}
__device__ __forceinline__ float h2f(us_t s) {
    __half h = *reinterpret_cast<__half*>(&s);
    return __half2float(h);
}
__device__ __forceinline__ h2_t u2h2(uint_t u) {
    union { uint_t u; h2_t h; } x; x.u = u; return x.h;
}

#if __has_builtin(__builtin_amdgcn_fdot2)
__device__ __forceinline__ float dot2f(uint_t a, uint_t b, float c) {
    return __builtin_amdgcn_fdot2(u2h2(a), u2h2(b), c, false);
}
#else
__device__ __forceinline__ float dot2f(uint_t a, uint_t b, float c) {
    h2_t x = u2h2(a), y = u2h2(b);
    return c + (float)x.x * (float)y.x + (float)x.y * (float)y.y;
}
#endif

#define DOT4C(q, mc, acc)                                               \
    acc = dot2f(q.x, mc.x, acc);                                        \
    acc = dot2f(q.y, mc.y, acc);                                        \
    acc = dot2f(q.z, mc.z, acc);                                        \
    acc = dot2f(q.w, mc.w, acc);

// ---------------- K1: convert/swizzle weights ----------------
// WdG  [c<64][tid<512][e<8] f16 (uint4 at c*512+tid lane-contiguous):
//      tid -> hg=tid>>6, i=tid&63;  c -> hh=c>>3, jp=c&7
//      h = (hg>>1)*16 + 2*hh + (hg&1),  j = jp*8 + e
//      val = Wd[h][i*64 + j]   (per-thread register layout for recur)
// decwY [mm<64][lane<64][k<4] bf16: val = decw[mm*256 + k*64 + lane]
// EWmG [jp<8][h2<128][k<8] f16: val = enc_m_row(j=jp*8+k, h2)
__global__ void cvt_kernel(const float* __restrict__ Wdecw,
                           const float* __restrict__ decw,
                           const float* __restrict__ Wencw,
                           const float* __restrict__ bencw,
                           us_t* __restrict__ WdG, us_t* __restrict__ decwY,
                           us_t* __restrict__ EWmG) {
    int o = blockIdx.x * 256 + threadIdx.x;
    if (o < 262144) {
        int e = o & 7;
        int tid = (o >> 3) & 511;
        int c = o >> 12;
        int hg = tid >> 6, i = tid & 63;
        int hh = c >> 3, jp = c & 7;
        int h = (hg >> 1) * 16 + 2 * hh + (hg & 1);
        int j = jp * 8 + e;
        WdG[o] = f2h(Wdecw[h * 4096 + i * 64 + j]);
    } else if (o < 278528) {
        int oo = o - 262144;
        int k = oo & 3, lane = (oo >> 2) & 63, mm = oo >> 8;
        decwY[oo] = f2bf(decw[mm * 256 + k * 64 + lane]);
    } else if (o < 286720) {
        int oo = o - 278528;
        int kk = oo & 7, h2 = (oo >> 3) & 127, jp = oo >> 10;
        int j = jp * 8 + kk;
        float v = (h2 < 64) ? Wencw[j * 64 + h2] : bencw[j * 64 + (h2 - 64)];
        EWmG[oo] = f2h(v);
    }
}

// ---------------- K2: token contribution table ----------------
__global__ void build_T(const float* __restrict__ emb, const float* __restrict__ Wencw,
                        const float* __restrict__ bencw, float* __restrict__ T) {
    int l = blockIdx.x >> 8, v = blockIdx.x & 255, h2 = threadIdx.x;  // h2 < 128
    float acc = 0.f;
#pragma unroll
    for (int e = 0; e < 16; ++e) {
        int d = 64 + l * 16 + e;
        float w = (h2 < 64) ? Wencw[d * 64 + h2] : bencw[d * 64 + (h2 - 64)];
        acc += emb[v * 16 + e] * w;
    }
    T[blockIdx.x * 128 + h2] = acc;
}

// ---------------- K3: window precompute P (f32) ----------------
__global__ void build_P(const float* __restrict__ T, const int* __restrict__ x0,
                        const float* __restrict__ Wencb, const float* __restrict__ bencb,
                        float* __restrict__ P) {
    int t = blockIdx.x >> 4, b = blockIdx.x & 15, h2 = threadIdx.x;  // h2 < 128
    float acc = (h2 < 64) ? Wencb[h2] : bencb[h2 - 64];
    for (int l = 0; l < 64; ++l) {
        int p = t + l;
        int v = (p < 64) ? 0 : x0[b * 2048 + (p - 64)];
        acc += T[(l * 256 + v) * 128 + h2];
    }
    P[blockIdx.x * 128 + h2] = acc;
}

// ---------------- K4: sequential recurrence (single WG per batch) ----------
// grid 16: b = blockIdx.x. 512 threads = 8 waves, 1 WG/CU, 2 waves/SIMD ->
// up to ~450 regs/wave. wreg[64] (256 VGPRs) holds this thread's slice of Wd.
__global__ __launch_bounds__(512, 2) void recur(
    const float* __restrict__ bdecw, const float* __restrict__ bdecb,
    const float* __restrict__ Wdecb, const us_t* __restrict__ WdG,
    const us_t* __restrict__ EWmG, const float* __restrict__ P,
    uint_t* __restrict__ mh32) {
    const int b = blockIdx.x;
    const int tid = threadIdx.x;

    __shared__ __align__(16) us_t EWm2[8192];     // 16 KB [jp][h2][8] f16
    __shared__ uint_t wdbt2[2048];                // 8 KB [jj<32][i<64] Wdb f16 pairs
    __shared__ uint_t bdec2[2048];                // 8 KB [hh<32][i<64] bdec f16 pairs
    __shared__ float  rp_s[512];                  // 2 KB [hg<8][i<64]
    __shared__ float  wdbm2_s[128];               // [q<2][i]
    __shared__ float  hbb2_s[128];                // [q<2][i]
    __shared__ float  hw_s[64];
    __shared__ uint_t hb2_s[32];                  // packed f16 hb pairs
    __shared__ __align__(16) uint_t m2_s[32];     // packed f16 m pairs
    __shared__ float  bias_s[64];

    // ---- init: full Wd slice -> 64 uint4 registers (compile-time indexed) ----
    uint4 wreg[64];
    {
        const uint4* g4 = (const uint4*)WdG;
#pragma unroll
        for (int c = 0; c < 64; ++c) wreg[c] = g4[c * 512 + tid];
    }
    {
        const uint4* g4 = (const uint4*)EWmG;
        uint4* l4 = (uint4*)EWm2;
        for (int k = tid; k < 1024; k += 512) l4[k] = g4[k];
    }
    for (int k = tid; k < 2048; k += 512) {
        int jj = k >> 6, i = k & 63;
        wdbt2[k] = (uint_t)f2h(Wdecb[i * 64 + 2 * jj])
                 | ((uint_t)f2h(Wdecb[i * 64 + 2 * jj + 1]) << 16);
        bdec2[k] = (uint_t)f2h(bdecw[(2 * jj) * 64 + i])
                 | ((uint_t)f2h(bdecw[(2 * jj + 1) * 64 + i]) << 16);
    }
    if (tid < 64) bias_s[tid] = bdecb[tid];
    if (tid < 32) m2_s[tid] = 0u;
    __syncthreads();

    float preg = 0.f;
    if (tid < 128) preg = P[b * 128 + tid];  // t = 0

    const uint4* EW4 = (const uint4*)EWm2;
    const uint4* m4 = (const uint4*)m2_s;
    const int hg = tid >> 6, iA = tid & 63;
    const int sA = hg >> 1, pA = hg & 1;

    for (int t = 0; t < 2048; ++t) {
        // ---- phase A: P prefetch; henc (waves 0-1); V (all); Wdb*m (waves 2-3)
        float pnext = 0.f;
        int tp = (t < 2047) ? (t + 1) : 2047;
        if (tid < 128) pnext = P[(tp * 16 + b) * 128 + tid];

        if (tid < 128) {
            float acc = preg;
#pragma unroll
            for (int jp = 0; jp < 8; ++jp) {
                uint4 e = EW4[jp * 128 + tid];
                uint4 mc = m4[jp];
                DOT4C(e, mc, acc);
            }
            float sg = 1.f / (1.f + __expf(-acc));
            if (tid < 64) {
                hw_s[tid] = sg;
            } else {
                int l = tid - 64;            // lane within wave 1
                float vlo = __shfl(sg, (l & 31) * 2, 64);
                float vhi = __shfl(sg, (l & 31) * 2 + 1, 64);
                if (l < 32)
                    hb2_s[l] = (uint_t)f2h(vlo) | ((uint_t)f2h(vhi) << 16);
            }
        }

        // V[h][iA] for this thread's 8 h-rows, entirely from registers.
        // m chunk per jp is an all-lanes-same-address LDS broadcast (free).
        float va[8];
#pragma unroll
        for (int hh = 0; hh < 8; ++hh) va[hh] = 0.f;
#pragma unroll
        for (int jp = 0; jp < 8; ++jp) {
            uint4 mc = m4[jp];
#pragma unroll
            for (int hh = 0; hh < 8; ++hh) {
                uint4 q = wreg[hh * 8 + jp];
                DOT4C(q, mc, va[hh]);
            }
        }

        if (hg == 2 || hg == 3) {            // Wdb*m local term (needs only m)
            int q = hg - 2;
            float wm = 0.f;
#pragma unroll
            for (int jj = 0; jj < 16; ++jj)
                wm = dot2f(wdbt2[(q * 16 + jj) * 64 + iA], m2_s[q * 16 + jj], wm);
            wdbm2_s[q * 64 + iA] = wm;
        }
        preg = pnext;
        __syncthreads();   // sync1

        // ---- phase B: hw-weighted partials from OWN V regs; bdec*hb ----
        {
            float pr = 0.f;
#pragma unroll
            for (int hh = 0; hh < 8; ++hh)
                pr += hw_s[sA * 16 + 2 * hh + pA] * va[hh];
            rp_s[hg * 64 + iA] = pr;
        }
        if (hg == 4 || hg == 5) {            // bdec*hb (needs hb from sync1)
            int q = hg - 4;
            float hbv = 0.f;
#pragma unroll
            for (int jj = 0; jj < 16; ++jj)
                hbv = dot2f(bdec2[(q * 16 + jj) * 64 + iA], hb2_s[q * 16 + jj], hbv);
            hbb2_s[q * 64 + iA] = hbv;
        }
        __syncthreads();   // sync2

        // ---- phase C: assemble m (order bit-identical to R13) ----
        if (tid < 64) {
            float rs0 = rp_s[tid] + rp_s[64 + tid];          // slice 0: r0+r1
            float rs1 = rp_s[128 + tid] + rp_s[192 + tid];   // slice 1
            float rs2 = rp_s[256 + tid] + rp_s[320 + tid];   // slice 2
            float rs3 = rp_s[384 + tid] + rp_s[448 + tid];   // slice 3
            float r = ((rs0 + rs1) + (rs2 + rs3))
                    + (wdbm2_s[tid] + wdbm2_s[64 + tid])
                    + (hbb2_s[tid] + hbb2_s[64 + tid])
                    + bias_s[tid];
            float nm = 1.f / (1.f + __expf(-r));
            us_t nh = f2h(nm);                  // f16 round (history dtype)
            uint_t nhu = (uint_t)nh;
            uint_t lo = (uint_t)__shfl((int)nhu, (tid & 31) * 2, 64);
            uint_t hi = (uint_t)__shfl((int)nhu, (tid & 31) * 2 + 1, 64);
            if (tid < 32) {
                uint_t pk = lo | (hi << 16);
                m2_s[tid] = pk;
                mh32[(t * 16 + b) * 32 + tid] = pk;  // history
            }
        }
        __syncthreads();   // sync3
    }
}

// ---------------- K5: parallel loss (reads f16 m history) ----------------
__global__ __launch_bounds__(256) void loss_kernel(
    const us_t* __restrict__ mhb, const us_t* __restrict__ decwY,
    const float* __restrict__ decb, const int* __restrict__ x0,
    float* __restrict__ out) {
    __shared__ __align__(16) us_t dw[16384];   // [mm][lane][k<4] bf16
    const int tid = threadIdx.x;
    {
        const uint4* g4 = (const uint4*)decwY;
        uint4* l4 = (uint4*)dw;
        for (int k = tid; k < 2048; k += 256) l4[k] = g4[k];
    }
    __syncthreads();
    const int lane = tid & 63, wv = tid >> 6;
    const uint2* dwu2 = (const uint2*)dw;
    float b0 = decb[lane], b1 = decb[lane + 64];
    float b2 = decb[lane + 128], b3 = decb[lane + 192];
    for (int r = 0; r < 8; ++r) {
        int row = blockIdx.x * 32 + wv * 8 + r;
        float mL = h2f(mhb[row * 64 + lane]);
        float l0 = b0, l1 = b1, l2 = b2, l3 = b3;
#pragma unroll
        for (int mm = 0; mm < 64; ++mm) {
            float mv = __shfl(mL, mm, 64);
            uint2 q = dwu2[mm * 64 + lane];
            l0 += mv * bflo(q.x);
            l1 += mv * bfhi(q.x);
            l2 += mv * bflo(q.y);
            l3 += mv * bfhi(q.y);
        }
        float mx = fmaxf(fmaxf(l0, l1), fmaxf(l2, l3));
#pragma unroll
        for (int o = 32; o > 0; o >>= 1) mx = fmaxf(mx, __shfl_xor(mx, o, 64));
        float se = __expf(l0 - mx) + __expf(l1 - mx) + __expf(l2 - mx) + __expf(l3 - mx);
#pragma unroll
        for (int o = 32; o > 0; o >>= 1) se += __shfl_xor(se, o, 64);
        float lse = mx + __logf(se);
        int t = row >> 4, bb = row & 15;
        int y = x0[bb * 2048 + t];
        int hi = y >> 6;
        float cand = hi == 0 ? l0 : (hi == 1 ? l1 : (hi == 2 ? l2 : l3));
        float ly = __shfl(cand, y & 63, 64);
        if (lane == 0) out[row] = (lse - ly) * 1.4426950408889634f;
    }
}

extern "C" void kernel_launch(void* const* d_in, const int* in_sizes, int n_in,
                              void* d_out, int out_size, void* d_ws, size_t ws_size,
                              hipStream_t stream) {
    const int*   x0    = (const int*)d_in[0];
    const float* emb   = (const float*)d_in[1];
    const float* Wencw = (const float*)d_in[2];
    const float* Wencb = (const float*)d_in[3];
    const float* Wdecw = (const float*)d_in[4];
    const float* Wdecb = (const float*)d_in[5];
    const float* bencw = (const float*)d_in[6];
    const float* bencb = (const float*)d_in[7];
    const float* bdecw = (const float*)d_in[8];
    const float* bdecb = (const float*)d_in[9];
    const float* decw  = (const float*)d_in[10];
    const float* decb  = (const float*)d_in[11];
    float* out = (float*)d_out;

    char* ws = (char*)d_ws;
    us_t*   WdG   = (us_t*)(ws);                 //       0 .. 524288
    us_t*   decwY = (us_t*)(ws + 524288);        //  524288 .. 557056
    us_t*   EWmG  = (us_t*)(ws + 557056);        //  557056 .. 573440 (16 KB)
    // 573440 .. 638976: (unused; was the R13 exchange mailbox)
    float*  T     = (float*)(ws + 638976);       //  638976 .. 9027584 (8 MB)
    uint_t* mh32  = (uint_t*)T;                  //  alias: T dead after build_P (4 MB)
    float*  P     = (float*)(ws + 9027584);      // 9027584 .. 25804800 (16 MB)

    cvt_kernel<<<1120, 256, 0, stream>>>(Wdecw, decw, Wencw, bencw,
                                         WdG, decwY, EWmG);
    build_T<<<16384, 128, 0, stream>>>(emb, Wencw, bencw, T);
    build_P<<<32768, 128, 0, stream>>>(T, x0, Wencb, bencb, P);
    recur<<<16, 512, 0, stream>>>(bdecw, bdecb, Wdecb, WdG, EWmG, P, mh32);
    loss_kernel<<<1024, 256, 0, stream>>>((const us_t*)mh32, decwY, decb, x0, out);
}

// Round 2
// 13254.909 us; speedup vs baseline: 1.0935x; 1.0935x over previous
//
#include <hip/hip_runtime.h>
#include <hip/hip_bf16.h>
#include <hip/hip_fp16.h>

// Hypernetwork RNN scan. B=16, N=2048, M=H=64, L*E=1024, Cout=256.
// Round 15: single-WG-per-batch, register-capacity-corrected.
// R14 post-mortem: gfx950 per-SIMD register file = 512 regs/lane TOTAL.
// 512-thread blocks (2 waves/SIMD) cap waves at 256 VGPRs; the 256-reg Wd
// array + working set forced a full scratch spill (VGPR_Count=128, 11-18 GB
// scratch FETCH, 5-18x regression). Fix: 256 threads = 1 wave/SIMD -> cap
// 512 VGPRs. Per-thread Wd slice = 128 uint4: 104 in VGPRs (416 regs, under
// the measured-safe ~450) + 24 rows in LDS (96 KB, resident; ds_read_b128
// per step overlaps the VALU dot2 stream on a different pipe).
//   thread (hg=tid>>6 in [0,4), i=tid&63) owns h-rows {hg*16+hl : hl<16}
//   per-step: 512 dot2/thread (VALU ~1100 cyc/SIMD) + 98 KB LDS reads
//   All f32 chains bit-identical to R13/R14 (absmax 0.0625 preserved).
//   K1 cvt: Wd->f16 per-thread layout; enc m-rows->f16; dec_w->bf16
//   K2 build_T (f32, 8 MB), K3 build_P (f32, 16 MB)
//   K4 recur: 16 WGs = 16 batches; Wd in VGPRs + resident LDS
//   K5 loss:  parallel logits/LSE/NLL over the f16 m history

typedef unsigned int uint_t;
typedef unsigned short us_t;
typedef _Float16 h2_t __attribute__((ext_vector_type(2)));

__device__ __forceinline__ us_t f2bf(float f) {
    uint_t u = __float_as_uint(f);
    uint_t r = u + 0x7fffu + ((u >> 16) & 1u);   // RNE
    return (us_t)(r >> 16);
}
__device__ __forceinline__ float bflo(uint_t u) { return __uint_as_float(u << 16); }
__device__ __forceinline__ float bfhi(uint_t u) { return __uint_as_float(u & 0xffff0000u); }

__device__ __forceinline__ us_t f2h(float f) {
    __half h = __float2half(f);                  // RNE
    return *reinterpret_cast<us_t*>(&h);
}
__device__ __forceinline__ float h2f(us_t s) {
    __half h = *reinterpret_cast<__half*>(&s);
    return __half2float(h);
}
__device__ __forceinline__ h2_t u2h2(uint_t u) {
    union { uint_t u; h2_t h; } x; x.u = u; return x.h;
}

#if __has_builtin(__builtin_amdgcn_fdot2)
__device__ __forceinline__ float dot2f(uint_t a, uint_t b, float c) {
    return __builtin_amdgcn_fdot2(u2h2(a), u2h2(b), c, false);
}
#else
__device__ __forceinline__ float dot2f(uint_t a, uint_t b, float c) {
    h2_t x = u2h2(a), y = u2h2(b);
    return c + (float)x.x * (float)y.x + (float)x.y * (float)y.y;
}
#endif

#define DOT4C(q, mc, acc)                                               \
    acc = dot2f(q.x, mc.x, acc);                                        \
    acc = dot2f(q.y, mc.y, acc);                                        \
    acc = dot2f(q.z, mc.z, acc);                                        \
    acc = dot2f(q.w, mc.w, acc);

// ---------------- K1: convert/swizzle weights ----------------
// WdG  [c<128][tid<256][e<8] f16 (uint4 at c*256+tid lane-contiguous):
//      tid -> hg=tid>>6, i=tid&63;  c -> hl=c>>3, jp=c&7
//      h = hg*16 + hl,  j = jp*8 + e
//      val = Wd[h][i*64 + j]   (per-thread register/LDS layout for recur)
// decwY [mm<64][lane<64][k<4] bf16: val = decw[mm*256 + k*64 + lane]
// EWmG [jp<8][h2<128][k<8] f16: val = enc_m_row(j=jp*8+k, h2)
__global__ void cvt_kernel(const float* __restrict__ Wdecw,
                           const float* __restrict__ decw,
                           const float* __restrict__ Wencw,
                           const float* __restrict__ bencw,
                           us_t* __restrict__ WdG, us_t* __restrict__ decwY,
                           us_t* __restrict__ EWmG) {
    int o = blockIdx.x * 256 + threadIdx.x;
    if (o < 262144) {
        int e = o & 7;
        int tq = (o >> 3) & 255;
        int c = o >> 11;
        int hg = tq >> 6, i = tq & 63;
        int hl = c >> 3, jp = c & 7;
        int h = hg * 16 + hl;
        int j = jp * 8 + e;
        WdG[o] = f2h(Wdecw[h * 4096 + i * 64 + j]);
    } else if (o < 278528) {
        int oo = o - 262144;
        int k = oo & 3, lane = (oo >> 2) & 63, mm = oo >> 8;
        decwY[oo] = f2bf(decw[mm * 256 + k * 64 + lane]);
    } else if (o < 286720) {
        int oo = o - 278528;
        int kk = oo & 7, h2 = (oo >> 3) & 127, jp = oo >> 10;
        int j = jp * 8 + kk;
        float v = (h2 < 64) ? Wencw[j * 64 + h2] : bencw[j * 64 + (h2 - 64)];
        EWmG[oo] = f2h(v);
    }
}

// ---------------- K2: token contribution table ----------------
__global__ void build_T(const float* __restrict__ emb, const float* __restrict__ Wencw,
                        const float* __restrict__ bencw, float* __restrict__ T) {
    int l = blockIdx.x >> 8, v = blockIdx.x & 255, h2 = threadIdx.x;  // h2 < 128
    float acc = 0.f;
#pragma unroll
    for (int e = 0; e < 16; ++e) {
        int d = 64 + l * 16 + e;
        float w = (h2 < 64) ? Wencw[d * 64 + h2] : bencw[d * 64 + (h2 - 64)];
        acc += emb[v * 16 + e] * w;
    }
    T[blockIdx.x * 128 + h2] = acc;
}

// ---------------- K3: window precompute P (f32) ----------------
__global__ void build_P(const float* __restrict__ T, const int* __restrict__ x0,
                        const float* __restrict__ Wencb, const float* __restrict__ bencb,
                        float* __restrict__ P) {
    int t = blockIdx.x >> 4, b = blockIdx.x & 15, h2 = threadIdx.x;  // h2 < 128
    float acc = (h2 < 64) ? Wencb[h2] : bencb[h2 - 64];
    for (int l = 0; l < 64; ++l) {
        int p = t + l;
        int v = (p < 64) ? 0 : x0[b * 2048 + (p - 64)];
        acc += T[(l * 256 + v) * 128 + h2];
    }
    P[blockIdx.x * 128 + h2] = acc;
}

// ---------------- K4: sequential recurrence (single WG per batch) ----------
// grid 16: b = blockIdx.x. 256 threads = 4 waves = 1 wave/SIMD -> VGPR cap
// 512. wreg[104] = 416 VGPRs; remaining 24 Wd rows resident in LDS.
__global__ __launch_bounds__(256, 1) void recur(
    const float* __restrict__ bdecw, const float* __restrict__ bdecb,
    const float* __restrict__ Wdecb, const us_t* __restrict__ WdG,
    const us_t* __restrict__ EWmG, const float* __restrict__ P,
    uint_t* __restrict__ mh32) {
    const int b = blockIdx.x;
    const int tid = threadIdx.x;

    extern __shared__ char smem[];
    uint4*  wlds4   = (uint4*)(smem);              // 98304 [c<24][tid<256] uint4
    us_t*   EWm2    = (us_t*)(smem + 98304);       // 16384 [jp][h2][8] f16
    uint_t* wdbt2   = (uint_t*)(smem + 114688);    // 8192 [jj<32][i<64] Wdb f16 pairs
    uint_t* bdec2   = (uint_t*)(smem + 122880);    // 8192 [hh<32][i<64] bdec f16 pairs
    float*  rp_s    = (float*)(smem + 131072);     // 1024 [hg<4][i<64]
    float*  wdbm2_s = (float*)(smem + 132096);     // 512  [q<2][i]
    float*  hbb2_s  = (float*)(smem + 132608);     // 512  [q<2][i]
    float*  hw_s    = (float*)(smem + 133120);     // 256
    uint_t* hb2_s   = (uint_t*)(smem + 133376);    // 128 packed f16 hb pairs
    uint_t* m2_s    = (uint_t*)(smem + 133504);    // 128 packed f16 m pairs
    float*  bias_s  = (float*)(smem + 133632);     // 256
    // total 133888 (dynamic; attribute set at launch). 1 WG/CU.

    // ---- init: Wd rows 0..103 -> registers, rows 104..127 -> LDS ----
    uint4 wreg[104];
    {
        const uint4* g4 = (const uint4*)WdG;
#pragma unroll
        for (int c = 0; c < 104; ++c) wreg[c] = g4[c * 256 + tid];
        for (int c = 104; c < 128; ++c) wlds4[(c - 104) * 256 + tid] = g4[c * 256 + tid];
    }
    {
        const uint4* g4 = (const uint4*)EWmG;
        uint4* l4 = (uint4*)EWm2;
        for (int k = tid; k < 1024; k += 256) l4[k] = g4[k];
    }
    for (int k = tid; k < 2048; k += 256) {
        int jj = k >> 6, i = k & 63;
        wdbt2[k] = (uint_t)f2h(Wdecb[i * 64 + 2 * jj])
                 | ((uint_t)f2h(Wdecb[i * 64 + 2 * jj + 1]) << 16);
        bdec2[k] = (uint_t)f2h(bdecw[(2 * jj) * 64 + i])
                 | ((uint_t)f2h(bdecw[(2 * jj + 1) * 64 + i]) << 16);
    }
    if (tid < 64) bias_s[tid] = bdecb[tid];
    if (tid < 32) m2_s[tid] = 0u;
    __syncthreads();

    float preg = 0.f;
    if (tid < 128) preg = P[b * 128 + tid];  // t = 0

    const uint4* EW4 = (const uint4*)EWm2;
    const uint4* m4 = (const uint4*)m2_s;
    const int hg = tid >> 6, iA = tid & 63;

    for (int t = 0; t < 2048; ++t) {
        // ---- phase A: P prefetch; henc (waves 0-1); V (all); Wdb*m (waves 2-3)
        float pnext = 0.f;
        int tp = (t < 2047) ? (t + 1) : 2047;
        if (tid < 128) pnext = P[(tp * 16 + b) * 128 + tid];

        if (tid < 128) {
            float acc = preg;
#pragma unroll
            for (int jp = 0; jp < 8; ++jp) {
                uint4 e = EW4[jp * 128 + tid];
                uint4 mc = m4[jp];
                DOT4C(e, mc, acc);
            }
            float sg = 1.f / (1.f + __expf(-acc));
            if (tid < 64) {
                hw_s[tid] = sg;
            } else {
                int l = tid - 64;            // lane within wave 1
                float vlo = __shfl(sg, (l & 31) * 2, 64);
                float vhi = __shfl(sg, (l & 31) * 2 + 1, 64);
                if (l < 32)
                    hb2_s[l] = (uint_t)f2h(vlo) | ((uint_t)f2h(vhi) << 16);
            }
        }

        // V[h][iA] for this thread's 16 h-rows. Rows 0..12 from registers,
        // 13..15 from resident LDS (reads issued at top of each jp iter).
        // Chain per (h,i): jp ascending, j ascending -> identical to R13/R14.
        float va[16];
#pragma unroll
        for (int hl = 0; hl < 16; ++hl) va[hl] = 0.f;
#pragma unroll
        for (int jp = 0; jp < 8; ++jp) {
            uint4 mc = m4[jp];
            uint4 q13 = wlds4[(0 * 8 + jp) * 256 + tid];
            uint4 q14 = wlds4[(1 * 8 + jp) * 256 + tid];
            uint4 q15 = wlds4[(2 * 8 + jp) * 256 + tid];
#pragma unroll
            for (int hl = 0; hl < 13; ++hl) {
                uint4 q = wreg[hl * 8 + jp];
                DOT4C(q, mc, va[hl]);
            }
            DOT4C(q13, mc, va[13]);
            DOT4C(q14, mc, va[14]);
            DOT4C(q15, mc, va[15]);
        }

        if (hg >= 2) {                       // Wdb*m local term (needs only m)
            int q = hg - 2;
            float wm = 0.f;
#pragma unroll
            for (int jj = 0; jj < 16; ++jj)
                wm = dot2f(wdbt2[(q * 16 + jj) * 64 + iA], m2_s[q * 16 + jj], wm);
            wdbm2_s[q * 64 + iA] = wm;
        }
        preg = pnext;
        __syncthreads();   // sync1

        // ---- phase B: hw-weighted slice sum from OWN V regs; bdec*hb ----
        {
            float r0 = 0.f, r1 = 0.f;
#pragma unroll
            for (int hh = 0; hh < 8; ++hh) {
                r0 += hw_s[hg * 16 + 2 * hh]     * va[2 * hh];
                r1 += hw_s[hg * 16 + 2 * hh + 1] * va[2 * hh + 1];
            }
            rp_s[hg * 64 + iA] = r0 + r1;    // slice hg's rs (= R13 r0+r1)
        }
        if (hg >= 2) {                       // bdec*hb (needs hb from sync1)
            int q = hg - 2;
            float hbv = 0.f;
#pragma unroll
            for (int jj = 0; jj < 16; ++jj)
                hbv = dot2f(bdec2[(q * 16 + jj) * 64 + iA], hb2_s[q * 16 + jj], hbv);
            hbb2_s[q * 64 + iA] = hbv;
        }
        __syncthreads();   // sync2

        // ---- phase C: assemble m (order bit-identical to R13/R14) ----
        if (tid < 64) {
            float rs01 = rp_s[tid] + rp_s[64 + tid];          // rs0 + rs1
            float rs23 = rp_s[128 + tid] + rp_s[192 + tid];   // rs2 + rs3
            float r = (rs01 + rs23)
                    + (wdbm2_s[tid] + wdbm2_s[64 + tid])
                    + (hbb2_s[tid] + hbb2_s[64 + tid])
                    + bias_s[tid];
            float nm = 1.f / (1.f + __expf(-r));
            us_t nh = f2h(nm);                  // f16 round (history dtype)
            uint_t nhu = (uint_t)nh;
            uint_t lo = (uint_t)__shfl((int)nhu, (tid & 31) * 2, 64);
            uint_t hi = (uint_t)__shfl((int)nhu, (tid & 31) * 2 + 1, 64);
            if (tid < 32) {
                uint_t pk = lo | (hi << 16);
                m2_s[tid] = pk;
                mh32[(t * 16 + b) * 32 + tid] = pk;  // history
            }
        }
        __syncthreads();   // sync3
    }
}

// ---------------- K5: parallel loss (reads f16 m history) ----------------
__global__ __launch_bounds__(256) void loss_kernel(
    const us_t* __restrict__ mhb, const us_t* __restrict__ decwY,
    const float* __restrict__ decb, const int* __restrict__ x0,
    float* __restrict__ out) {
    __shared__ __align__(16) us_t dw[16384];   // [mm][lane][k<4] bf16
    const int tid = threadIdx.x;
    {
        const uint4* g4 = (const uint4*)decwY;
        uint4* l4 = (uint4*)dw;
        for (int k = tid; k < 2048; k += 256) l4[k] = g4[k];
    }
    __syncthreads();
    const int lane = tid & 63, wv = tid >> 6;
    const uint2* dwu2 = (const uint2*)dw;
    float b0 = decb[lane], b1 = decb[lane + 64];
    float b2 = decb[lane + 128], b3 = decb[lane + 192];
    for (int r = 0; r < 8; ++r) {
        int row = blockIdx.x * 32 + wv * 8 + r;
        float mL = h2f(mhb[row * 64 + lane]);
        float l0 = b0, l1 = b1, l2 = b2, l3 = b3;
#pragma unroll
        for (int mm = 0; mm < 64; ++mm) {
            float mv = __shfl(mL, mm, 64);
            uint2 q = dwu2[mm * 64 + lane];
            l0 += mv * bflo(q.x);
            l1 += mv * bfhi(q.x);
            l2 += mv * bflo(q.y);
            l3 += mv * bfhi(q.y);
        }
        float mx = fmaxf(fmaxf(l0, l1), fmaxf(l2, l3));
#pragma unroll
        for (int o = 32; o > 0; o >>= 1) mx = fmaxf(mx, __shfl_xor(mx, o, 64));
        float se = __expf(l0 - mx) + __expf(l1 - mx) + __expf(l2 - mx) + __expf(l3 - mx);
#pragma unroll
        for (int o = 32; o > 0; o >>= 1) se += __shfl_xor(se, o, 64);
        float lse = mx + __logf(se);
        int t = row >> 4, bb = row & 15;
        int y = x0[bb * 2048 + t];
        int hi = y >> 6;
        float cand = hi == 0 ? l0 : (hi == 1 ? l1 : (hi == 2 ? l2 : l3));
        float ly = __shfl(cand, y & 63, 64);
        if (lane == 0) out[row] = (lse - ly) * 1.4426950408889634f;
    }
}

extern "C" void kernel_launch(void* const* d_in, const int* in_sizes, int n_in,
                              void* d_out, int out_size, void* d_ws, size_t ws_size,
                              hipStream_t stream) {
    const int*   x0    = (const int*)d_in[0];
    const float* emb   = (const float*)d_in[1];
    const float* Wencw = (const float*)d_in[2];
    const float* Wencb = (const float*)d_in[3];
    const float* Wdecw = (const float*)d_in[4];
    const float* Wdecb = (const float*)d_in[5];
    const float* bencw = (const float*)d_in[6];
    const float* bencb = (const float*)d_in[7];
    const float* bdecw = (const float*)d_in[8];
    const float* bdecb = (const float*)d_in[9];
    const float* decw  = (const float*)d_in[10];
    const float* decb  = (const float*)d_in[11];
    float* out = (float*)d_out;

    char* ws = (char*)d_ws;
    us_t*   WdG   = (us_t*)(ws);                 //       0 .. 524288
    us_t*   decwY = (us_t*)(ws + 524288);        //  524288 .. 557056
    us_t*   EWmG  = (us_t*)(ws + 557056);        //  557056 .. 573440 (16 KB)
    float*  T     = (float*)(ws + 638976);       //  638976 .. 9027584 (8 MB)
    uint_t* mh32  = (uint_t*)T;                  //  alias: T dead after build_P (4 MB)
    float*  P     = (float*)(ws + 9027584);      // 9027584 .. 25804800 (16 MB)

    static const int kRecurLds = 133888;
    (void)hipFuncSetAttribute((const void*)recur,
                              hipFuncAttributeMaxDynamicSharedMemorySize,
                              kRecurLds);

    cvt_kernel<<<1120, 256, 0, stream>>>(Wdecw, decw, Wencw, bencw,
                                         WdG, decwY, EWmG);
    build_T<<<16384, 128, 0, stream>>>(emb, Wencw, bencw, T);
    build_P<<<32768, 128, 0, stream>>>(T, x0, Wencb, bencb, P);
    recur<<<16, 256, kRecurLds, stream>>>(bdecw, bdecb, Wdecb, WdG, EWmG,
                                          P, mh32);
    loss_kernel<<<1024, 256, 0, stream>>>((const us_t*)mh32, decwY, decb, x0, out);
}